// Round 1
// baseline (4661.133 us; speedup 1.0000x reference)
//
#include <hip/hip_runtime.h>
#include <math.h>

// Problem constants
#define NXc 128
#define NQc 128
#define NUc 64
#define NYc 64
#define BATCHc 200000

// workspace layout (float offsets); total ~459 KB
#define WS_P    0
#define WS_Y    16384
#define WS_R    32768
#define WS_A    49152
#define WS_B1   65536
#define WS_C1   81920
#define WS_D11  98304

__device__ __forceinline__ float fast_tanh(float x) {
  float e = __expf(2.0f * x);
  return 1.0f - 2.0f / (e + 1.0f);
}

// K1: compute P, Y, R, C1, D11 into ws. 5*16384 elements, one thread each.
__global__ __launch_bounds__(256) void k1_params(
    const float* __restrict__ Pstar, const float* __restrict__ Chi,
    const float* __restrict__ Y1, const float* __restrict__ X,
    float* __restrict__ ws)
{
  int gid = blockIdx.x * 256 + threadIdx.x;
  int mat = gid >> 14;
  int idx = gid & 16383;
  int i = idx >> 7, j = idx & 127;
  if (mat == 0) {
    // P = 0.5*Pstar@Pstar.T + eps I
    float s = 0.f;
    for (int k = 0; k < 128; ++k) s = fmaf(Pstar[i*128+k], Pstar[j*128+k], s);
    ws[WS_P + idx] = 0.5f*s + (i==j ? 0.01f : 0.f);
  } else if (mat == 1) {
    // Y = -0.5*(H1 + Y1 - Y1^T), H1 = (X X^T)[:128,:128] + eps I
    float s = 0.f;
    for (int k = 0; k < 256; ++k) s = fmaf(X[i*256+k], X[j*256+k], s);
    float h1 = s + (i==j ? 0.01f : 0.f);
    ws[WS_Y + idx] = -0.5f*(h1 + Y1[i*128+j] - Y1[j*128+i]);
  } else if (mat == 2) {
    // R = -H2 - Chi, H2[i][j] = sum_k X[i,k] X[128+j,k]
    float s = 0.f;
    for (int k = 0; k < 256; ++k) s = fmaf(X[i*256+k], X[(128+j)*256+k], s);
    ws[WS_R + idx] = -s - Chi[i*128+j];
  } else if (mat == 3) {
    // C1[q][x] = Chi[x][q] / lam[q];  lam[q] = 0.5*(||X[128+q]||^2 + eps)
    float lam = 0.f;
    for (int k = 0; k < 256; ++k) { float v = X[(128+i)*256+k]; lam = fmaf(v, v, lam); }
    lam = 0.5f*(lam + 0.01f);
    ws[WS_C1 + idx] = Chi[j*128+i] / lam;
  } else {
    // D11[i][j] = (j<i) ? -H4[i][j]/lam[i] : 0
    float lam = 0.f, s = 0.f;
    for (int k = 0; k < 256; ++k) {
      float vi = X[(128+i)*256+k];
      lam = fmaf(vi, vi, lam);
      s = fmaf(vi, X[(128+j)*256+k], s);
    }
    lam = 0.5f*(lam + 0.01f);
    ws[WS_D11 + idx] = (j < i) ? (-s / lam) : 0.f;
  }
}

// K2: in-place Gauss-Jordan inversion of P (SPD, no pivoting), 1 block.
__global__ __launch_bounds__(256) void k2_invert(float* __restrict__ ws)
{
  __shared__ float Pls[128*130];
  __shared__ float fcol[128];
  const int t = threadIdx.x;
  for (int idx = t; idx < 16384; idx += 256) {
    int i = idx >> 7, j = idx & 127;
    Pls[i*130 + j] = ws[WS_P + idx];
  }
  __syncthreads();
  for (int k = 0; k < 128; ++k) {
    // S0: snapshot pivot + column k
    float pinv = 1.0f / Pls[k*130+k];
    if (t < 128) fcol[t] = Pls[t*130+k];
    __syncthreads();
    // S1: scale row k; set column k to final values
    if (t < 128) {
      int j = t;
      if (j == k) Pls[k*130+j] = pinv;
      else        Pls[k*130+j] *= pinv;
    } else {
      int i = t - 128;
      if (i != k) Pls[i*130+k] = -fcol[i]*pinv;
    }
    __syncthreads();
    // S2: rank-1 update of the rest
    for (int idx = t; idx < 16384; idx += 256) {
      int i = idx >> 7, j = idx & 127;
      if (i != k && j != k) Pls[i*130+j] = fmaf(-fcol[i], Pls[k*130+j], Pls[i*130+j]);
    }
    __syncthreads();
  }
  for (int idx = t; idx < 16384; idx += 256) {
    int i = idx >> 7, j = idx & 127;
    ws[WS_P + idx] = Pls[i*130+j];
  }
}

// K3: A = Pinv@Y, B1 = Pinv@R. 128 blocks (one output row each), 256 threads.
__global__ __launch_bounds__(256) void k3_solve(float* __restrict__ ws)
{
  const int i = blockIdx.x;
  const int t = threadIdx.x;
  const int j = t & 127;
  const int which = t >> 7;
  const float* Pinv = ws + WS_P;
  const float* Src  = ws + (which ? WS_R : WS_Y);
  float* Dst        = ws + (which ? WS_B1 : WS_A);
  float s = 0.f;
  for (int k = 0; k < 128; ++k) s = fmaf(Pinv[i*128+k], Src[k*128+j], s);
  Dst[i*128+j] = s;
}

// K4: fused forward over a 64-row batch tile per block. 256 threads = 4 waves.
// thread role in GEMM phases: r = tid&63 (row), g = tid>>6 (column group, stride 4)
// recurrence: each wave handles 16 rows, 4 lanes per row.
__global__ __launch_bounds__(256) void k4_forward(
    const float* __restrict__ xi, const float* __restrict__ u,
    const float* __restrict__ ws,
    const float* __restrict__ B2, const float* __restrict__ D12,
    const float* __restrict__ C2, const float* __restrict__ D21,
    const float* __restrict__ D22,
    float* __restrict__ out)
{
  __shared__ float s_bw[64*133];  // base, overlaid with w during recurrence
  __shared__ float s_u[64*65];
  __shared__ float s_xc[64*33];

  const float* Am   = ws + WS_A;
  const float* B1m  = ws + WS_B1;
  const float* C1m  = ws + WS_C1;
  const float* D11m = ws + WS_D11;

  const int tid = threadIdx.x;
  const int r = tid & 63;
  const int g = __builtin_amdgcn_readfirstlane(tid >> 6);  // wave-uniform
  const int row0 = blockIdx.x * 64;

  // stage u tile (coalesced)
  for (int idx = tid; idx < 64*64; idx += 256) {
    int rr = idx >> 6, cc = idx & 63;
    s_u[rr*65 + cc] = u[(row0 + rr)*64 + cc];
  }

  // ---- base = xi@C1^T + u@D12^T ----
  float acc[32];
  #pragma unroll
  for (int q = 0; q < 32; ++q) acc[q] = 0.f;

  for (int kk = 0; kk < 4; ++kk) {
    __syncthreads();
    for (int idx = tid; idx < 64*32; idx += 256) {
      int rr = idx >> 5, cc = idx & 31;
      s_xc[rr*33 + cc] = xi[(row0 + rr)*128 + kk*32 + cc];
    }
    __syncthreads();
    float xr[32];
    #pragma unroll
    for (int k2 = 0; k2 < 32; ++k2) xr[k2] = s_xc[r*33 + k2];
    #pragma unroll
    for (int q = 0; q < 32; ++q) {
      const float* cp = C1m + (g + 4*q)*128 + kk*32;
      #pragma unroll
      for (int k2 = 0; k2 < 32; ++k2) acc[q] = fmaf(xr[k2], cp[k2], acc[q]);
    }
  }
  for (int m = 0; m < 64; ++m) {
    float uv = s_u[r*65 + m];
    #pragma unroll
    for (int q = 0; q < 32; ++q) acc[q] = fmaf(uv, D12[(g + 4*q)*64 + m], acc[q]);
  }
  #pragma unroll
  for (int q = 0; q < 32; ++q) s_bw[r*133 + (g + 4*q)] = acc[q];
  __syncthreads();

  // ---- recurrence: w[i] = tanh(base[i] + sum_{j<i} D11[i][j]*w[j]) ----
  {
    const int l = tid & 63;
    const int c = l & 3;           // 4 lanes per row
    const int rr = g*16 + (l >> 2);
    const int rb = rr*133;
    for (int i = 0; i < 128; ++i) {
      float p0 = 0.f;
      for (int j = c; j < i; j += 4)
        p0 = fmaf(D11m[i*128 + j], s_bw[rb + j], p0);
      p0 += __shfl_xor(p0, 1);
      p0 += __shfl_xor(p0, 2);
      float x = s_bw[rb + i] + p0;   // base, read before overwrite
      float v = fast_tanh(x);
      if (c == 0) s_bw[rb + i] = v;  // wave-synchronous, DS in-order
    }
  }
  __syncthreads();

  // ---- xi_dot = xi@A^T + w@B1^T + u@B2^T ; yi = xi@C2^T + w@D21^T + u@D22^T ----
  float ax[32], ay[16];
  #pragma unroll
  for (int q = 0; q < 32; ++q) ax[q] = 0.f;
  #pragma unroll
  for (int q = 0; q < 16; ++q) ay[q] = 0.f;

  for (int j = 0; j < 128; ++j) {
    float wv = s_bw[r*133 + j];
    #pragma unroll
    for (int q = 0; q < 32; ++q) ax[q] = fmaf(wv, B1m[(g + 4*q)*128 + j], ax[q]);
    #pragma unroll
    for (int q = 0; q < 16; ++q) ay[q] = fmaf(wv, D21[(g + 4*q)*128 + j], ay[q]);
  }
  for (int m = 0; m < 64; ++m) {
    float uv = s_u[r*65 + m];
    #pragma unroll
    for (int q = 0; q < 32; ++q) ax[q] = fmaf(uv, B2[(g + 4*q)*64 + m], ax[q]);
    #pragma unroll
    for (int q = 0; q < 16; ++q) ay[q] = fmaf(uv, D22[(g + 4*q)*64 + m], ay[q]);
  }
  for (int kk = 0; kk < 4; ++kk) {
    __syncthreads();
    for (int idx = tid; idx < 64*32; idx += 256) {
      int rr = idx >> 5, cc = idx & 31;
      s_xc[rr*33 + cc] = xi[(row0 + rr)*128 + kk*32 + cc];
    }
    __syncthreads();
    float xr[32];
    #pragma unroll
    for (int k2 = 0; k2 < 32; ++k2) xr[k2] = s_xc[r*33 + k2];
    #pragma unroll
    for (int q = 0; q < 32; ++q) {
      const float* ap = Am + (g + 4*q)*128 + kk*32;
      #pragma unroll
      for (int k2 = 0; k2 < 32; ++k2) ax[q] = fmaf(xr[k2], ap[k2], ax[q]);
    }
    #pragma unroll
    for (int q = 0; q < 16; ++q) {
      const float* cp = C2 + (g + 4*q)*128 + kk*32;
      #pragma unroll
      for (int k2 = 0; k2 < 32; ++k2) ay[q] = fmaf(xr[k2], cp[k2], ay[q]);
    }
  }

  #pragma unroll
  for (int q = 0; q < 32; ++q)
    out[(row0 + r)*128 + (g + 4*q)] = ax[q];
  const int yoff = BATCHc * 128;
  #pragma unroll
  for (int q = 0; q < 16; ++q)
    out[yoff + (row0 + r)*64 + (g + 4*q)] = ay[q];
}

extern "C" void kernel_launch(void* const* d_in, const int* in_sizes, int n_in,
                              void* d_out, int out_size, void* d_ws, size_t ws_size,
                              hipStream_t stream) {
  // inputs: 0:t 1:xi 2:u 3:Pstar 4:Chi 5:Y1 6:X 7:B2 8:D12 9:C2 10:D21 11:D22
  const float* xi    = (const float*)d_in[1];
  const float* u     = (const float*)d_in[2];
  const float* Pstar = (const float*)d_in[3];
  const float* Chi   = (const float*)d_in[4];
  const float* Y1    = (const float*)d_in[5];
  const float* X     = (const float*)d_in[6];
  const float* B2    = (const float*)d_in[7];
  const float* D12   = (const float*)d_in[8];
  const float* C2    = (const float*)d_in[9];
  const float* D21   = (const float*)d_in[10];
  const float* D22   = (const float*)d_in[11];
  float* out = (float*)d_out;
  float* ws  = (float*)d_ws;   // uses ~459 KB

  k1_params<<<320, 256, 0, stream>>>(Pstar, Chi, Y1, X, ws);
  k2_invert<<<1, 256, 0, stream>>>(ws);
  k3_solve<<<128, 256, 0, stream>>>(ws);
  k4_forward<<<(BATCHc/64), 256, 0, stream>>>(xi, u, ws, B2, D12, C2, D21, D22, out);
}

// Round 2
// 4634.887 us; speedup vs baseline: 1.0057x; 1.0057x over previous
//
#include <hip/hip_runtime.h>
#include <math.h>

// Problem constants
#define NXc 128
#define NQc 128
#define NUc 64
#define NYc 64
#define BATCHc 200000

// workspace layout (float offsets); total ~459 KB
#define WS_P    0
#define WS_Y    16384
#define WS_R    32768
#define WS_A    49152
#define WS_B1   65536
#define WS_C1   81920
#define WS_D11  98304

__device__ __forceinline__ float fast_tanh(float x) {
  float e = __expf(2.0f * x);
  return 1.0f - 2.0f / (e + 1.0f);
}

// K1: compute P, Y, R, C1, D11 into ws. 5*16384 elements, one thread each.
__global__ __launch_bounds__(256) void k1_params(
    const float* __restrict__ Pstar, const float* __restrict__ Chi,
    const float* __restrict__ Y1, const float* __restrict__ X,
    float* __restrict__ ws)
{
  int gid = blockIdx.x * 256 + threadIdx.x;
  int mat = gid >> 14;
  int idx = gid & 16383;
  int i = idx >> 7, j = idx & 127;
  if (mat == 0) {
    // P = 0.5*Pstar@Pstar.T + eps I
    float s = 0.f;
    for (int k = 0; k < 128; ++k) s = fmaf(Pstar[i*128+k], Pstar[j*128+k], s);
    ws[WS_P + idx] = 0.5f*s + (i==j ? 0.01f : 0.f);
  } else if (mat == 1) {
    // Y = -0.5*(H1 + Y1 - Y1^T), H1 = (X X^T)[:128,:128] + eps I
    float s = 0.f;
    for (int k = 0; k < 256; ++k) s = fmaf(X[i*256+k], X[j*256+k], s);
    float h1 = s + (i==j ? 0.01f : 0.f);
    ws[WS_Y + idx] = -0.5f*(h1 + Y1[i*128+j] - Y1[j*128+i]);
  } else if (mat == 2) {
    // R = -H2 - Chi, H2[i][j] = sum_k X[i,k] X[128+j,k]
    float s = 0.f;
    for (int k = 0; k < 256; ++k) s = fmaf(X[i*256+k], X[(128+j)*256+k], s);
    ws[WS_R + idx] = -s - Chi[i*128+j];
  } else if (mat == 3) {
    // C1[q][x] = Chi[x][q] / lam[q];  lam[q] = 0.5*(||X[128+q]||^2 + eps)
    float lam = 0.f;
    for (int k = 0; k < 256; ++k) { float v = X[(128+i)*256+k]; lam = fmaf(v, v, lam); }
    lam = 0.5f*(lam + 0.01f);
    ws[WS_C1 + idx] = Chi[j*128+i] / lam;
  } else {
    // D11[i][j] = (j<i) ? -H4[i][j]/lam[i] : 0
    float lam = 0.f, s = 0.f;
    for (int k = 0; k < 256; ++k) {
      float vi = X[(128+i)*256+k];
      lam = fmaf(vi, vi, lam);
      s = fmaf(vi, X[(128+j)*256+k], s);
    }
    lam = 0.5f*(lam + 0.01f);
    ws[WS_D11 + idx] = (j < i) ? (-s / lam) : 0.f;
  }
}

// K2: in-place Gauss-Jordan inversion of P (SPD, no pivoting), 1 block.
__global__ __launch_bounds__(256) void k2_invert(float* __restrict__ ws)
{
  __shared__ float Pls[128*130];
  __shared__ float fcol[128];
  const int t = threadIdx.x;
  for (int idx = t; idx < 16384; idx += 256) {
    int i = idx >> 7, j = idx & 127;
    Pls[i*130 + j] = ws[WS_P + idx];
  }
  __syncthreads();
  for (int k = 0; k < 128; ++k) {
    // S0: snapshot pivot + column k
    float pinv = 1.0f / Pls[k*130+k];
    if (t < 128) fcol[t] = Pls[t*130+k];
    __syncthreads();
    // S1: scale row k; set column k to final values
    if (t < 128) {
      int j = t;
      if (j == k) Pls[k*130+j] = pinv;
      else        Pls[k*130+j] *= pinv;
    } else {
      int i = t - 128;
      if (i != k) Pls[i*130+k] = -fcol[i]*pinv;
    }
    __syncthreads();
    // S2: rank-1 update of the rest
    for (int idx = t; idx < 16384; idx += 256) {
      int i = idx >> 7, j = idx & 127;
      if (i != k && j != k) Pls[i*130+j] = fmaf(-fcol[i], Pls[k*130+j], Pls[i*130+j]);
    }
    __syncthreads();
  }
  for (int idx = t; idx < 16384; idx += 256) {
    int i = idx >> 7, j = idx & 127;
    ws[WS_P + idx] = Pls[i*130+j];
  }
}

// K3: A = Pinv@Y, B1 = Pinv@R. 128 blocks (one output row each), 256 threads.
__global__ __launch_bounds__(256) void k3_solve(float* __restrict__ ws)
{
  const int i = blockIdx.x;
  const int t = threadIdx.x;
  const int j = t & 127;
  const int which = t >> 7;
  const float* Pinv = ws + WS_P;
  const float* Src  = ws + (which ? WS_R : WS_Y);
  float* Dst        = ws + (which ? WS_B1 : WS_A);
  float s = 0.f;
  for (int k = 0; k < 128; ++k) s = fmaf(Pinv[i*128+k], Src[k*128+j], s);
  Dst[i*128+j] = s;
}

// K4: fused forward over a 64-row batch tile per block. 256 threads = 4 waves.
// thread role in GEMM phases: r = tid&63 (row), g = tid>>6 (column group, stride 4)
// recurrence: each wave handles 16 rows, 4 lanes per row.
__global__ __launch_bounds__(256) void k4_forward(
    const float* __restrict__ xi, const float* __restrict__ u,
    const float* __restrict__ ws,
    const float* __restrict__ B2, const float* __restrict__ D12,
    const float* __restrict__ C2, const float* __restrict__ D21,
    const float* __restrict__ D22,
    float* __restrict__ out)
{
  __shared__ float s_bw[64*133];  // base, overlaid with w during recurrence
  __shared__ float s_u[64*65];
  __shared__ float s_xc[64*33];

  const float* Am   = ws + WS_A;
  const float* B1m  = ws + WS_B1;
  const float* C1m  = ws + WS_C1;
  const float* D11m = ws + WS_D11;

  const int tid = threadIdx.x;
  const int r = tid & 63;
  const int g = __builtin_amdgcn_readfirstlane(tid >> 6);  // wave-uniform
  const int row0 = blockIdx.x * 64;

  // stage u tile (coalesced)
  for (int idx = tid; idx < 64*64; idx += 256) {
    int rr = idx >> 6, cc = idx & 63;
    s_u[rr*65 + cc] = u[(row0 + rr)*64 + cc];
  }

  // ---- base = xi@C1^T + u@D12^T ----
  float acc[32];
  #pragma unroll
  for (int q = 0; q < 32; ++q) acc[q] = 0.f;

  for (int kk = 0; kk < 4; ++kk) {
    __syncthreads();
    for (int idx = tid; idx < 64*32; idx += 256) {
      int rr = idx >> 5, cc = idx & 31;
      s_xc[rr*33 + cc] = xi[(row0 + rr)*128 + kk*32 + cc];
    }
    __syncthreads();
    float xr[32];
    #pragma unroll
    for (int k2 = 0; k2 < 32; ++k2) xr[k2] = s_xc[r*33 + k2];
    #pragma unroll
    for (int q = 0; q < 32; ++q) {
      const float* cp = C1m + (g + 4*q)*128 + kk*32;
      #pragma unroll
      for (int k2 = 0; k2 < 32; ++k2) acc[q] = fmaf(xr[k2], cp[k2], acc[q]);
    }
  }
  for (int m = 0; m < 64; ++m) {
    float uv = s_u[r*65 + m];
    #pragma unroll
    for (int q = 0; q < 32; ++q) acc[q] = fmaf(uv, D12[(g + 4*q)*64 + m], acc[q]);
  }
  #pragma unroll
  for (int q = 0; q < 32; ++q) s_bw[r*133 + (g + 4*q)] = acc[q];
  __syncthreads();

  // ---- recurrence: w[i] = tanh(base[i] + sum_{j<i} D11[i][j]*w[j]) ----
  {
    const int l = tid & 63;
    const int c = l & 3;           // 4 lanes per row
    const int rr = g*16 + (l >> 2);
    const int rb = rr*133;
    for (int i = 0; i < 128; ++i) {
      float p0 = 0.f;
      for (int j = c; j < i; j += 4)
        p0 = fmaf(D11m[i*128 + j], s_bw[rb + j], p0);
      p0 += __shfl_xor(p0, 1);
      p0 += __shfl_xor(p0, 2);
      float x = s_bw[rb + i] + p0;   // base, read before overwrite
      float v = fast_tanh(x);
      if (c == 0) s_bw[rb + i] = v;  // wave-synchronous, DS in-order
    }
  }
  __syncthreads();

  // ---- xi_dot = xi@A^T + w@B1^T + u@B2^T ; yi = xi@C2^T + w@D21^T + u@D22^T ----
  float ax[32], ay[16];
  #pragma unroll
  for (int q = 0; q < 32; ++q) ax[q] = 0.f;
  #pragma unroll
  for (int q = 0; q < 16; ++q) ay[q] = 0.f;

  for (int j = 0; j < 128; ++j) {
    float wv = s_bw[r*133 + j];
    #pragma unroll
    for (int q = 0; q < 32; ++q) ax[q] = fmaf(wv, B1m[(g + 4*q)*128 + j], ax[q]);
    #pragma unroll
    for (int q = 0; q < 16; ++q) ay[q] = fmaf(wv, D21[(g + 4*q)*128 + j], ay[q]);
  }
  for (int m = 0; m < 64; ++m) {
    float uv = s_u[r*65 + m];
    #pragma unroll
    for (int q = 0; q < 32; ++q) ax[q] = fmaf(uv, B2[(g + 4*q)*64 + m], ax[q]);
    #pragma unroll
    for (int q = 0; q < 16; ++q) ay[q] = fmaf(uv, D22[(g + 4*q)*64 + m], ay[q]);
  }
  for (int kk = 0; kk < 4; ++kk) {
    __syncthreads();
    for (int idx = tid; idx < 64*32; idx += 256) {
      int rr = idx >> 5, cc = idx & 31;
      s_xc[rr*33 + cc] = xi[(row0 + rr)*128 + kk*32 + cc];
    }
    __syncthreads();
    float xr[32];
    #pragma unroll
    for (int k2 = 0; k2 < 32; ++k2) xr[k2] = s_xc[r*33 + k2];
    #pragma unroll
    for (int q = 0; q < 32; ++q) {
      const float* ap = Am + (g + 4*q)*128 + kk*32;
      #pragma unroll
      for (int k2 = 0; k2 < 32; ++k2) ax[q] = fmaf(xr[k2], ap[k2], ax[q]);
    }
    #pragma unroll
    for (int q = 0; q < 16; ++q) {
      const float* cp = C2 + (g + 4*q)*128 + kk*32;
      #pragma unroll
      for (int k2 = 0; k2 < 32; ++k2) ay[q] = fmaf(xr[k2], cp[k2], ay[q]);
    }
  }

  #pragma unroll
  for (int q = 0; q < 32; ++q)
    out[(row0 + r)*128 + (g + 4*q)] = ax[q];
  const int yoff = BATCHc * 128;
  #pragma unroll
  for (int q = 0; q < 16; ++q)
    out[yoff + (row0 + r)*64 + (g + 4*q)] = ay[q];
}

extern "C" void kernel_launch(void* const* d_in, const int* in_sizes, int n_in,
                              void* d_out, int out_size, void* d_ws, size_t ws_size,
                              hipStream_t stream) {
  // inputs: 0:t 1:xi 2:u 3:Pstar 4:Chi 5:Y1 6:X 7:B2 8:D12 9:C2 10:D21 11:D22
  const float* xi    = (const float*)d_in[1];
  const float* u     = (const float*)d_in[2];
  const float* Pstar = (const float*)d_in[3];
  const float* Chi   = (const float*)d_in[4];
  const float* Y1    = (const float*)d_in[5];
  const float* X     = (const float*)d_in[6];
  const float* B2    = (const float*)d_in[7];
  const float* D12   = (const float*)d_in[8];
  const float* C2    = (const float*)d_in[9];
  const float* D21   = (const float*)d_in[10];
  const float* D22   = (const float*)d_in[11];
  float* out = (float*)d_out;
  float* ws  = (float*)d_ws;   // uses ~459 KB

  k1_params<<<320, 256, 0, stream>>>(Pstar, Chi, Y1, X, ws);
  k2_invert<<<1, 256, 0, stream>>>(ws);
  k3_solve<<<128, 256, 0, stream>>>(ws);
  k4_forward<<<(BATCHc/64), 256, 0, stream>>>(xi, u, ws, B2, D12, C2, D21, D22, out);
}